// Round 1
// baseline (1469.740 us; speedup 1.0000x reference)
//
#include <hip/hip_runtime.h>
#include <hip/hip_bf16.h>

#define BATCH 64
#define SEQ   2048
#define HID   1024
#define EDIM  2048   // 2*HID

typedef __bf16 bf16x8 __attribute__((ext_vector_type(8)));
typedef float  f32x4  __attribute__((ext_vector_type(4)));

__device__ inline unsigned short f2bf(float x) {
    __hip_bfloat16 h = __float2bfloat16(x);
    return __builtin_bit_cast(unsigned short, h);
}

__device__ inline uint4 pack8(float4 f0, float4 f1) {
    uint4 r;
    r.x = (unsigned)f2bf(f0.x) | ((unsigned)f2bf(f0.y) << 16);
    r.y = (unsigned)f2bf(f0.z) | ((unsigned)f2bf(f0.w) << 16);
    r.z = (unsigned)f2bf(f1.x) | ((unsigned)f2bf(f1.y) << 16);
    r.w = (unsigned)f2bf(f1.z) | ((unsigned)f2bf(f1.w) << 16);
    return r;
}

// ---------------- prep: W_h (EDIM x HID fp32, row-major) -> Wt (HID x EDIM bf16)
__global__ void wh_transpose_kernel(const float* __restrict__ Wh,
                                    unsigned short* __restrict__ Wt) {
    __shared__ float tile[32][33];
    int bx = blockIdx.x % (EDIM / 32);   // e-tile
    int by = blockIdx.x / (EDIM / 32);   // h-tile
    int e0 = bx * 32, h0 = by * 32;
    int tx = threadIdx.x % 32, ty = threadIdx.x / 32;  // 32x8
    #pragma unroll
    for (int i = 0; i < 4; ++i)
        tile[ty + 8 * i][tx] = Wh[(size_t)(e0 + ty + 8 * i) * HID + h0 + tx];
    __syncthreads();
    #pragma unroll
    for (int i = 0; i < 4; ++i)
        Wt[(size_t)(h0 + ty + 8 * i) * EDIM + e0 + tx] = f2bf(tile[tx][ty + 8 * i]);
}

// ---------------- prep: dec_proj = decoder_hidden @ W_d  (fp32, (B,HID))
__global__ void dec_proj_kernel(const float* __restrict__ dec,
                                const float* __restrict__ Wd,
                                float* __restrict__ dp) {
    int gid = blockIdx.x * 256 + threadIdx.x;
    int b = gid >> 10, h = gid & 1023;
    const float* dr = dec + b * HID;
    float acc = 0.f;
    #pragma unroll 4
    for (int k = 0; k < HID; ++k) acc = fmaf(dr[k], Wd[(size_t)k * HID + h], acc);
    dp[gid] = acc;
}

// ---------------- main: fused enc@W_h + dec_proj + cov*W_c -> tanh -> dot v -> scores
#define MT  128
#define NCH 512
#define BK  32
#define KSTEPS 64
#define APAD 40
#define BPAD 40

__global__ __launch_bounds__(512, 2) void scores_kernel(
    const float* __restrict__ enc, const float* __restrict__ cov,
    const unsigned short* __restrict__ Wt, const float* __restrict__ dp,
    const float* __restrict__ Wc, const float* __restrict__ vv,
    float* __restrict__ scores)
{
    __shared__ unsigned short Al[2][MT][APAD];     // [row][k] bf16, pad->80B stride
    __shared__ unsigned short Bl[2][NCH][BPAD];    // [n][k]  bf16
    __shared__ float dp_s[HID], wc_s[HID], v_s[HID];
    __shared__ float cov_s[MT];
    __shared__ float sred[MT][4];

    const int tid = threadIdx.x;
    const int b  = blockIdx.x >> 4;
    const int s0 = (blockIdx.x & 15) * MT;
    const int lane = tid & 63;
    const int wid  = tid >> 6;
    const int wm = wid >> 2;     // 0..1 : 64-row half
    const int wn = wid & 3;      // 0..3 : 128-col quarter
    const int c15 = lane & 15;
    const int g   = lane >> 4;

    for (int i = tid; i < HID; i += 512) {
        dp_s[i] = dp[b * HID + i];
        wc_s[i] = Wc[i];
        v_s[i]  = vv[i];
    }
    if (tid < MT) cov_s[tid] = cov[b * SEQ + s0 + tid];

    const float* Abase = enc + (size_t)(b * SEQ + s0) * EDIM;
    const int arow = tid >> 2;
    const int akq  = (tid & 3) * 8;

    float spart[4][4];
    #pragma unroll
    for (int mi = 0; mi < 4; ++mi)
        #pragma unroll
        for (int r = 0; r < 4; ++r) spart[mi][r] = 0.f;

    for (int c = 0; c < 2; ++c) {
        f32x4 acc[4][8];
        #pragma unroll
        for (int mi = 0; mi < 4; ++mi)
            #pragma unroll
            for (int nj = 0; nj < 8; ++nj)
                #pragma unroll
                for (int r = 0; r < 4; ++r) acc[mi][nj][r] = 0.f;

        const unsigned short* Bbase = Wt + (size_t)(c * NCH + tid) * EDIM;

        // prologue: stage k-step 0 into buffer 0
        {
            const float* ap = Abase + (size_t)arow * EDIM + akq;
            float4 f0 = *(const float4*)ap;
            float4 f1 = *(const float4*)(ap + 4);
            *(uint4*)&Al[0][arow][akq] = pack8(f0, f1);
            const uint4* bp = (const uint4*)Bbase;
            uint4* bw = (uint4*)&Bl[0][tid][0];
            bw[0] = bp[0]; bw[1] = bp[1]; bw[2] = bp[2]; bw[3] = bp[3];
        }
        __syncthreads();

        for (int kk = 0; kk < KSTEPS; ++kk) {
            const int cur = kk & 1;
            float4 a0, a1; uint4 nb0, nb1, nb2, nb3;
            const bool hasNext = (kk + 1 < KSTEPS);
            if (hasNext) {   // issue next-tile global loads early (latency hides under MFMA)
                const float* ap = Abase + (size_t)arow * EDIM + (kk + 1) * BK + akq;
                a0 = *(const float4*)ap;
                a1 = *(const float4*)(ap + 4);
                const uint4* bp = (const uint4*)(Bbase + (size_t)(kk + 1) * BK);
                nb0 = bp[0]; nb1 = bp[1]; nb2 = bp[2]; nb3 = bp[3];
            }
            bf16x8 bfr[8];
            #pragma unroll
            for (int nj = 0; nj < 8; ++nj)
                bfr[nj] = __builtin_bit_cast(bf16x8,
                    *(const uint4*)&Bl[cur][wn * 128 + nj * 16 + c15][g * 8]);
            #pragma unroll
            for (int mi = 0; mi < 4; ++mi) {
                bf16x8 afr = __builtin_bit_cast(bf16x8,
                    *(const uint4*)&Al[cur][wm * 64 + mi * 16 + c15][g * 8]);
                #pragma unroll
                for (int nj = 0; nj < 8; ++nj)
                    acc[mi][nj] = __builtin_amdgcn_mfma_f32_16x16x32_bf16(
                        afr, bfr[nj], acc[mi][nj], 0, 0, 0);
            }
            if (hasNext) {
                const int nxt = cur ^ 1;
                *(uint4*)&Al[nxt][arow][akq] = pack8(a0, a1);
                uint4* bw = (uint4*)&Bl[nxt][tid][0];
                bw[0] = nb0; bw[1] = nb1; bw[2] = nb2; bw[3] = nb3;
            }
            __syncthreads();
        }

        // epilogue: pre-act -> tanh -> * v, accumulate per-row partials
        #pragma unroll
        for (int mi = 0; mi < 4; ++mi) {
            #pragma unroll
            for (int nj = 0; nj < 8; ++nj) {
                const int h = c * NCH + wn * 128 + nj * 16 + c15;
                const float dv = dp_s[h], wcv = wc_s[h], vvv = v_s[h];
                #pragma unroll
                for (int r = 0; r < 4; ++r) {
                    const int row = wm * 64 + mi * 16 + g * 4 + r;
                    float pre = acc[mi][nj][r] + dv + cov_s[row] * wcv;
                    float pc = fminf(pre, 20.0f);     // tanh(20)==1 in fp32; avoid inf/inf
                    float e2 = __expf(2.0f * pc);
                    float th = (e2 - 1.0f) / (e2 + 1.0f);
                    spart[mi][r] = fmaf(th, vvv, spart[mi][r]);
                }
            }
        }
    }

    // reduce over the 16 col-lanes, then across the 4 n-waves via LDS
    #pragma unroll
    for (int mi = 0; mi < 4; ++mi) {
        #pragma unroll
        for (int r = 0; r < 4; ++r) {
            float x = spart[mi][r];
            x += __shfl_xor(x, 1);
            x += __shfl_xor(x, 2);
            x += __shfl_xor(x, 4);
            x += __shfl_xor(x, 8);
            if (c15 == 0) sred[wm * 64 + mi * 16 + g * 4 + r][wn] = x;
        }
    }
    __syncthreads();
    if (tid < MT)
        scores[b * SEQ + s0 + tid] = sred[tid][0] + sred[tid][1] + sred[tid][2] + sred[tid][3];
}

// ---------------- softmax + coverage_new
__global__ void softmax_kernel(const float* __restrict__ scores,
                               const int* __restrict__ mask,
                               const float* __restrict__ cov,
                               float* __restrict__ out)
{
    __shared__ float red[8];
    int b = blockIdx.x, tid = threadIdx.x;   // 256 threads
    float vals[8];
    float mx = -1e30f;
    #pragma unroll
    for (int i = 0; i < 8; ++i) {
        int s = tid + i * 256;
        float sc = scores[b * SEQ + s];
        sc = (mask[b * SEQ + s] == 0) ? -10000.0f : sc;
        vals[i] = sc;
        mx = fmaxf(mx, sc);
    }
    for (int m = 1; m < 64; m <<= 1) mx = fmaxf(mx, __shfl_xor(mx, m));
    if ((tid & 63) == 0) red[tid >> 6] = mx;
    __syncthreads();
    mx = fmaxf(fmaxf(red[0], red[1]), fmaxf(red[2], red[3]));
    float sum = 0.f;
    #pragma unroll
    for (int i = 0; i < 8; ++i) { vals[i] = __expf(vals[i] - mx); sum += vals[i]; }
    for (int m = 1; m < 64; m <<= 1) sum += __shfl_xor(sum, m);
    if ((tid & 63) == 0) red[4 + (tid >> 6)] = sum;
    __syncthreads();
    sum = red[4] + red[5] + red[6] + red[7];
    float inv = 1.0f / sum;
    float* attn = out + BATCH * EDIM;          // after context
    float* covn = attn + BATCH * SEQ;
    #pragma unroll
    for (int i = 0; i < 8; ++i) {
        int s = tid + i * 256;
        float w = vals[i] * inv;
        attn[b * SEQ + s] = w;
        covn[b * SEQ + s] = cov[b * SEQ + s] + w;
    }
}

// ---------------- context = attn @ encoder_outputs  (streaming, 1 GiB read)
__global__ void context_kernel(const float* __restrict__ enc,
                               const float* __restrict__ attn,
                               float* __restrict__ ctx)
{
    __shared__ float w_s[SEQ];
    int b  = blockIdx.x >> 3;
    int e0 = (blockIdx.x & 7) * 256;
    int tid = threadIdx.x;
    for (int i = tid; i < SEQ; i += 256) w_s[i] = attn[b * SEQ + i];
    __syncthreads();
    const float* ep = enc + (size_t)b * SEQ * EDIM + e0 + tid;
    float acc = 0.f;
    #pragma unroll 8
    for (int s = 0; s < SEQ; ++s) acc = fmaf(w_s[s], ep[(size_t)s * EDIM], acc);
    ctx[b * EDIM + e0 + tid] = acc;
}

extern "C" void kernel_launch(void* const* d_in, const int* in_sizes, int n_in,
                              void* d_out, int out_size, void* d_ws, size_t ws_size,
                              hipStream_t stream) {
    const float* dec  = (const float*)d_in[0];
    const float* enc  = (const float*)d_in[1];
    const float* cov  = (const float*)d_in[2];
    const int*   mask = (const int*)d_in[3];
    const float* Wh   = (const float*)d_in[4];
    const float* Wd   = (const float*)d_in[5];
    const float* Wc   = (const float*)d_in[6];
    const float* v    = (const float*)d_in[7];
    float* out = (float*)d_out;

    unsigned short* Wt = (unsigned short*)d_ws;                        // 4 MiB bf16
    float* dp     = (float*)((char*)d_ws + (size_t)HID * EDIM * 2);    // 256 KiB
    float* scores = dp + BATCH * HID;                                  // 512 KiB

    wh_transpose_kernel<<<dim3((EDIM / 32) * (HID / 32)), dim3(256), 0, stream>>>(Wh, Wt);
    dec_proj_kernel<<<dim3(BATCH * HID / 256), dim3(256), 0, stream>>>(dec, Wd, dp);
    scores_kernel<<<dim3(BATCH * (SEQ / MT)), dim3(512), 0, stream>>>(enc, cov, Wt, dp, Wc, v, scores);
    softmax_kernel<<<dim3(BATCH), dim3(256), 0, stream>>>(scores, mask, cov, out);
    context_kernel<<<dim3(BATCH * (EDIM / 256)), dim3(256), 0, stream>>>(enc, out + BATCH * EDIM, out);
}

// Round 2
// 1071.628 us; speedup vs baseline: 1.3715x; 1.3715x over previous
//
#include <hip/hip_runtime.h>
#include <hip/hip_bf16.h>
#include <stdint.h>

#define BATCH 64
#define SEQ   2048
#define HID   1024
#define EDIM  2048   // 2*HID

#define BM 64
#define BK 32
#define KSTEPS (EDIM / BK)   // 64
// smem: Bl[2][4*1024*8]sh (128KB) + Al[2][64][32]sh (8KB) + cov(256B) + sred(2KB)
#define SMEM_BYTES 141568

typedef __bf16 bf16x8 __attribute__((ext_vector_type(8)));
typedef float  f32x4  __attribute__((ext_vector_type(4)));

__device__ __forceinline__ unsigned short f2bf(float x) {
    __hip_bfloat16 h = __float2bfloat16(x);
    return __builtin_bit_cast(unsigned short, h);
}

__device__ __forceinline__ uint4 pack8(float4 f0, float4 f1) {
    uint4 r;
    r.x = (unsigned)f2bf(f0.x) | ((unsigned)f2bf(f0.y) << 16);
    r.y = (unsigned)f2bf(f0.z) | ((unsigned)f2bf(f0.w) << 16);
    r.z = (unsigned)f2bf(f1.x) | ((unsigned)f2bf(f1.y) << 16);
    r.w = (unsigned)f2bf(f1.z) | ((unsigned)f2bf(f1.w) << 16);
    return r;
}

__device__ __forceinline__ void gload16(const void* g, void* l) {
    __builtin_amdgcn_global_load_lds(
        (const __attribute__((address_space(1))) void*)g,
        (__attribute__((address_space(3))) void*)l, 16, 0, 0);
}

// ---------------- prep: W_h (EDIM x HID fp32) -> Wt bf16 in k-granule-major
// layout: element (h, e) at Wt[(e>>3)*8192 + h*8 + (e&7)]
__global__ void wh_transpose_kernel(const float* __restrict__ Wh,
                                    unsigned short* __restrict__ Wt) {
    __shared__ float tile[32][33];
    int bx = blockIdx.x & 63;    // e-tile (2048/32)
    int by = blockIdx.x >> 6;    // h-tile (1024/32)
    int e0 = bx * 32, h0 = by * 32;
    int tx = threadIdx.x & 31, ty = threadIdx.x >> 5;   // 32 x 8
    #pragma unroll
    for (int i = 0; i < 4; ++i)
        tile[ty + 8 * i][tx] = Wh[(size_t)(e0 + ty + 8 * i) * HID + h0 + tx];
    __syncthreads();
    if (ty < 4) {   // 4 granules x 32 h per tile; each thread packs 8 shorts (16B)
        uint4 wv;
        unsigned short* ws = (unsigned short*)&wv;
        #pragma unroll
        for (int j = 0; j < 8; ++j) ws[j] = f2bf(tile[ty * 8 + j][tx]);
        *(uint4*)&Wt[((size_t)(e0 >> 3) + ty) * 8192 + (size_t)(h0 + tx) * 8] = wv;
    }
}

// ---------------- prep: dec_proj = decoder_hidden @ W_d  (fp32, (B,HID))
__global__ void dec_proj_kernel(const float* __restrict__ dec,
                                const float* __restrict__ Wd,
                                float* __restrict__ dp) {
    int gid = blockIdx.x * 256 + threadIdx.x;
    int b = gid >> 10, h = gid & 1023;
    const float* dr = dec + b * HID;
    float acc = 0.f;
    #pragma unroll 4
    for (int k = 0; k < HID; ++k) acc = fmaf(dr[k], Wd[(size_t)k * HID + h], acc);
    dp[gid] = acc;
}

// ---------------- main fused scores kernel: 64 x 1024-full-N tile, 16 waves
__global__ __launch_bounds__(1024, 4) void scores_kernel(
    const float* __restrict__ enc, const float* __restrict__ cov,
    const unsigned short* __restrict__ Wt, const float* __restrict__ dp,
    const float* __restrict__ Wc, const float* __restrict__ vv,
    float* __restrict__ scores)
{
    extern __shared__ char smem[];
    unsigned short* Blbase = (unsigned short*)smem;            // 2 x 32768 shorts
    unsigned short* Albase = (unsigned short*)(smem + 131072); // 2 x 2048 shorts
    float* cov_s = (float*)(smem + 139264);                    // 64 floats
    float* sred  = (float*)(smem + 139520);                    // 64 x 8 floats

    const int tid  = threadIdx.x;
    const int lane = tid & 63;
    const int wid  = tid >> 6;        // 0..15
    const int wm   = wid >> 3;        // 0..1 : 32-row half
    const int wn   = wid & 7;         // 0..7 : 128-col slice
    const int c15  = lane & 15;
    const int g    = lane >> 4;
    const int rsl  = (c15 & 3) ^ ((c15 >> 2) & 3);   // A read-side swizzle base

    const int b  = blockIdx.x >> 5;            // 2048 blocks = 64 b x 32 s-tiles
    const int s0 = (blockIdx.x & 31) * BM;

    const float* Abase = enc + (size_t)(b * SEQ + s0) * EDIM;

    // A staging mapping: threads 0..255, one k-granule (8 floats -> 16B bf16) each
    const int arow = tid >> 2;                 // 0..63
    const int ag   = tid & 3;
    const int asl  = ag ^ ((arow & 3) ^ ((arow >> 2) & 3));

    f32x4 acc[2][8];
    #pragma unroll
    for (int mi = 0; mi < 2; ++mi)
        #pragma unroll
        for (int nj = 0; nj < 8; ++nj)
            #pragma unroll
            for (int r = 0; r < 4; ++r) acc[mi][nj][r] = 0.f;

    if (tid < BM) cov_s[tid] = cov[b * SEQ + s0 + tid];

    // prologue: stage k-step 0 into buffer 0
    {
        const unsigned short* bsrc = Wt + (size_t)tid * 8;
        unsigned short* bdst = Blbase + tid * 8;
        #pragma unroll
        for (int j = 0; j < 4; ++j)
            gload16(bsrc + (size_t)j * 8192, bdst + j * 8192);
        if (tid < 256) {
            const float* ap = Abase + (size_t)arow * EDIM + ag * 8;
            *(uint4*)(Albase + arow * 32 + asl * 8) =
                pack8(*(const float4*)ap, *(const float4*)(ap + 4));
        }
    }
    __syncthreads();

    float4 a0n, a1n;
    for (int kk = 0; kk < KSTEPS; ++kk) {
        const int cur = kk & 1, nxt = cur ^ 1;
        const unsigned short* Bcur = Blbase + cur * 32768;
        const unsigned short* Acur = Albase + cur * 2048;

        if (kk + 1 < KSTEPS) {
            // issue next B tile: contiguous 64KB of granule-major Wt -> linear LDS
            const unsigned short* bsrc = Wt + (size_t)(kk + 1) * 32768 + (size_t)tid * 8;
            unsigned short* bdst = Blbase + nxt * 32768 + tid * 8;
            #pragma unroll
            for (int j = 0; j < 4; ++j)
                gload16(bsrc + (size_t)j * 8192, bdst + j * 8192);
            if (tid < 256) {   // issue next A loads early (write after MFMA)
                const float* ap = Abase + (size_t)arow * EDIM + (kk + 1) * BK + ag * 8;
                a0n = *(const float4*)ap;
                a1n = *(const float4*)(ap + 4);
            }
        }

        bf16x8 afr0 = *(const bf16x8*)(Acur + (wm * 32 + c15) * 32 + ((g ^ rsl) * 8));
        bf16x8 afr1 = *(const bf16x8*)(Acur + (wm * 32 + 16 + c15) * 32 + ((g ^ rsl) * 8));
        #pragma unroll
        for (int nj = 0; nj < 8; ++nj) {
            bf16x8 bfr = *(const bf16x8*)(Bcur + ((size_t)(g * 1024 + wn * 128 + nj * 16 + c15)) * 8);
            acc[0][nj] = __builtin_amdgcn_mfma_f32_16x16x32_bf16(afr0, bfr, acc[0][nj], 0, 0, 0);
            acc[1][nj] = __builtin_amdgcn_mfma_f32_16x16x32_bf16(afr1, bfr, acc[1][nj], 0, 0, 0);
        }

        if (kk + 1 < KSTEPS && tid < 256)
            *(uint4*)(Albase + nxt * 2048 + arow * 32 + asl * 8) = pack8(a0n, a1n);
        __syncthreads();
    }

    // epilogue: + dec_proj + cov*W_c -> tanh -> * v, reduce over H
    float spart[2][4] = {{0.f,0.f,0.f,0.f},{0.f,0.f,0.f,0.f}};
    #pragma unroll
    for (int nj = 0; nj < 8; ++nj) {
        const int h = wn * 128 + nj * 16 + c15;
        const float dv  = dp[b * HID + h];
        const float wcv = Wc[h];
        const float vvv = vv[h];
        #pragma unroll
        for (int mi = 0; mi < 2; ++mi) {
            #pragma unroll
            for (int r = 0; r < 4; ++r) {
                const int row = wm * 32 + mi * 16 + g * 4 + r;
                float pre = acc[mi][nj][r] + dv + cov_s[row] * wcv;
                float pc = fminf(pre, 20.0f);
                float e2 = __expf(2.0f * pc);
                float th = (e2 - 1.0f) / (e2 + 1.0f);
                spart[mi][r] = fmaf(th, vvv, spart[mi][r]);
            }
        }
    }
    #pragma unroll
    for (int mi = 0; mi < 2; ++mi) {
        #pragma unroll
        for (int r = 0; r < 4; ++r) {
            float x = spart[mi][r];
            x += __shfl_xor(x, 1);
            x += __shfl_xor(x, 2);
            x += __shfl_xor(x, 4);
            x += __shfl_xor(x, 8);
            if (c15 == 0) sred[(wm * 32 + mi * 16 + g * 4 + r) * 8 + wn] = x;
        }
    }
    __syncthreads();
    if (tid < BM) {
        float s = 0.f;
        #pragma unroll
        for (int w = 0; w < 8; ++w) s += sred[tid * 8 + w];
        scores[b * SEQ + s0 + tid] = s;
    }
}

// ---------------- softmax + coverage_new
__global__ void softmax_kernel(const float* __restrict__ scores,
                               const int* __restrict__ mask,
                               const float* __restrict__ cov,
                               float* __restrict__ out)
{
    __shared__ float red[8];
    int b = blockIdx.x, tid = threadIdx.x;   // 256 threads
    float vals[8];
    float mx = -1e30f;
    #pragma unroll
    for (int i = 0; i < 8; ++i) {
        int s = tid + i * 256;
        float sc = scores[b * SEQ + s];
        sc = (mask[b * SEQ + s] == 0) ? -10000.0f : sc;
        vals[i] = sc;
        mx = fmaxf(mx, sc);
    }
    for (int m = 1; m < 64; m <<= 1) mx = fmaxf(mx, __shfl_xor(mx, m));
    if ((tid & 63) == 0) red[tid >> 6] = mx;
    __syncthreads();
    mx = fmaxf(fmaxf(red[0], red[1]), fmaxf(red[2], red[3]));
    float sum = 0.f;
    #pragma unroll
    for (int i = 0; i < 8; ++i) { vals[i] = __expf(vals[i] - mx); sum += vals[i]; }
    for (int m = 1; m < 64; m <<= 1) sum += __shfl_xor(sum, m);
    if ((tid & 63) == 0) red[4 + (tid >> 6)] = sum;
    __syncthreads();
    sum = red[4] + red[5] + red[6] + red[7];
    float inv = 1.0f / sum;
    float* attn = out + BATCH * EDIM;          // after context
    float* covn = attn + BATCH * SEQ;
    #pragma unroll
    for (int i = 0; i < 8; ++i) {
        int s = tid + i * 256;
        float w = vals[i] * inv;
        attn[b * SEQ + s] = w;
        covn[b * SEQ + s] = cov[b * SEQ + s] + w;
    }
}

// ---------------- context = attn @ encoder_outputs  (streaming, 1 GiB read)
__global__ void context_kernel(const float* __restrict__ enc,
                               const float* __restrict__ attn,
                               float* __restrict__ ctx)
{
    __shared__ float w_s[SEQ];
    int b  = blockIdx.x >> 3;
    int e0 = (blockIdx.x & 7) * 256;
    int tid = threadIdx.x;
    for (int i = tid; i < SEQ; i += 256) w_s[i] = attn[b * SEQ + i];
    __syncthreads();
    const float* ep = enc + (size_t)b * SEQ * EDIM + e0 + tid;
    float acc = 0.f;
    #pragma unroll 8
    for (int s = 0; s < SEQ; ++s) acc = fmaf(w_s[s], ep[(size_t)s * EDIM], acc);
    ctx[b * EDIM + e0 + tid] = acc;
}

extern "C" void kernel_launch(void* const* d_in, const int* in_sizes, int n_in,
                              void* d_out, int out_size, void* d_ws, size_t ws_size,
                              hipStream_t stream) {
    const float* dec  = (const float*)d_in[0];
    const float* enc  = (const float*)d_in[1];
    const float* cov  = (const float*)d_in[2];
    const int*   mask = (const int*)d_in[3];
    const float* Wh   = (const float*)d_in[4];
    const float* Wd   = (const float*)d_in[5];
    const float* Wc   = (const float*)d_in[6];
    const float* v    = (const float*)d_in[7];
    float* out = (float*)d_out;

    unsigned short* Wt = (unsigned short*)d_ws;                        // 4 MiB bf16
    float* dp     = (float*)((char*)d_ws + (size_t)HID * EDIM * 2);    // 256 KiB
    float* scores = dp + BATCH * HID;                                  // 512 KiB

    // allow 141568 B dynamic LDS (idempotent; not a stream op -> capture-safe)
    (void)hipFuncSetAttribute((const void*)scores_kernel,
                              hipFuncAttributeMaxDynamicSharedMemorySize, SMEM_BYTES);

    wh_transpose_kernel<<<dim3(64 * 32), dim3(256), 0, stream>>>(Wh, Wt);
    dec_proj_kernel<<<dim3(BATCH * HID / 256), dim3(256), 0, stream>>>(dec, Wd, dp);
    scores_kernel<<<dim3(BATCH * (SEQ / BM)), dim3(1024), SMEM_BYTES, stream>>>(
        enc, cov, Wt, dp, Wc, v, scores);
    softmax_kernel<<<dim3(BATCH), dim3(256), 0, stream>>>(scores, mask, cov, out);
    context_kernel<<<dim3(BATCH * (EDIM / 256)), dim3(256), 0, stream>>>(enc, out + BATCH * EDIM, out);
}